// Round 1
// baseline (734.366 us; speedup 1.0000x reference)
//
#include <hip/hip_runtime.h>
#include <stdint.h>
#include <math.h>

// Problem dims
#define BDIM 8192
#define TDIM 8192
#define FDIM 768
#define PDIM 512
#define HDIM 1024
#define NEXP 4
#define NCAT 5376  // 4*1024 (experts) + 1024 (ds) + 256 (router)

using short8 = __attribute__((ext_vector_type(8))) short;
using f32x4  = __attribute__((ext_vector_type(4))) float;

__device__ __forceinline__ short f2bf(float f) {
  uint32_t u = __builtin_bit_cast(uint32_t, f);
  u += 0x7fffu + ((u >> 16) & 1u);   // RNE
  return (short)(u >> 16);
}
__device__ __forceinline__ float bf2f(short s) {
  uint32_t u = ((uint32_t)(uint16_t)s) << 16;
  return __builtin_bit_cast(float, u);
}
__device__ __forceinline__ float gelu_exact(float x) {
  return 0.5f * x * (1.0f + erff(x * 0.70710678118654752f));
}

#define GLDS(gp, lp) __builtin_amdgcn_global_load_lds( \
    (const __attribute__((address_space(1))) void*)(gp), \
    (__attribute__((address_space(3))) void*)(lp), 16, 0, 0)

// ---------------------------------------------------------------------------
// C[M,N] = A[M,K] @ B[N,K]^T  (both row-major [rows,K], bf16-as-short)
// 128x128 block tile, 4 waves, each wave 64x64 (4x4 of 16x16x32 MFMA), BK=32.
// MODE 0: +bias[col], gelu, store bf16
// MODE 1: +bias[col], store f32
// MODE 2: *expf(*scale_ptr), store f32
// ---------------------------------------------------------------------------
template <int MODE>
__global__ __launch_bounds__(256, 2)
void gemm_bt(const short* __restrict__ A, int lda,
             const short* __restrict__ B, int ldb,
             void* __restrict__ C, int ldc, int K,
             const float* __restrict__ bias,
             const float* __restrict__ scale_ptr)
{
  __shared__ short sA[4096];  // 128 x 32
  __shared__ short sB[4096];
  const int t    = threadIdx.x;
  const int lane = t & 63;
  const int wave = t >> 6;
  const int m0 = blockIdx.y * 128;
  const int n0 = blockIdx.x * 128;
  const int wm = (wave >> 1) * 64;
  const int wn = (wave & 1) * 64;
  const int l15  = lane & 15;
  const int quad = lane >> 4;

  f32x4 acc[4][4];
#pragma unroll
  for (int i = 0; i < 4; ++i)
#pragma unroll
    for (int j = 0; j < 4; ++j)
      acc[i][j] = (f32x4){0.f, 0.f, 0.f, 0.f};

  // staging: thread t covers row t/4 (+64 for second issue), cols (t%4)*8..+8
  const int rr = t >> 2;
  const int cc = (t & 3) * 8;
  const short* gA0 = A + (size_t)(m0 + rr) * lda + cc;
  const short* gA1 = A + (size_t)(m0 + 64 + rr) * lda + cc;
  const short* gB0 = B + (size_t)(n0 + rr) * ldb + cc;
  const short* gB1 = B + (size_t)(n0 + 64 + rr) * ldb + cc;
  short* lA0 = sA + t * 8;          // == rr*32 + cc : lane-contiguous per wave
  short* lA1 = sA + 2048 + t * 8;
  short* lB0 = sB + t * 8;
  short* lB1 = sB + 2048 + t * 8;

  for (int k0 = 0; k0 < K; k0 += 32) {
    GLDS(gA0 + k0, lA0);
    GLDS(gA1 + k0, lA1);
    GLDS(gB0 + k0, lB0);
    GLDS(gB1 + k0, lB1);
    __syncthreads();
    short8 af[4], bfr[4];
#pragma unroll
    for (int i = 0; i < 4; ++i)
      af[i] = *(const short8*)(sA + (wm + i * 16 + l15) * 32 + quad * 8);
#pragma unroll
    for (int j = 0; j < 4; ++j)
      bfr[j] = *(const short8*)(sB + (wn + j * 16 + l15) * 32 + quad * 8);
#pragma unroll
    for (int i = 0; i < 4; ++i)
#pragma unroll
      for (int j = 0; j < 4; ++j)
        acc[i][j] = __builtin_amdgcn_mfma_f32_16x16x32_bf16(af[i], bfr[j], acc[i][j], 0, 0, 0);
    __syncthreads();
  }

  float scale = 1.f;
  if (MODE == 2) scale = expf(scale_ptr[0]);
#pragma unroll
  for (int i = 0; i < 4; ++i) {
#pragma unroll
    for (int j = 0; j < 4; ++j) {
      const int col = n0 + wn + j * 16 + l15;
      float bv = (MODE == 2) ? 0.f : bias[col];
#pragma unroll
      for (int r = 0; r < 4; ++r) {
        const int row = m0 + wm + i * 16 + quad * 4 + r;  // C/D: col=lane&15, row=quad*4+reg
        float v = acc[i][j][r];
        if (MODE == 0) {
          v = gelu_exact(v + bv);
          ((short*)C)[(size_t)row * ldc + col] = f2bf(v);
        } else if (MODE == 1) {
          ((float*)C)[(size_t)row * ldc + col] = v + bv;
        } else {
          ((float*)C)[(size_t)row * ldc + col] = v * scale;
        }
      }
    }
  }
}

// ---------------------------------------------------------------------------
__global__ __launch_bounds__(256)
void f32_to_bf16(const float* __restrict__ src, short* __restrict__ dst, int n) {
  int i = blockIdx.x * 256 + threadIdx.x;
  if (i < n) dst[i] = f2bf(src[i]);
}

__global__ __launch_bounds__(256)
void concat_bias(const float* __restrict__ exp_b, const float* __restrict__ ds_b1,
                 const float* __restrict__ rt_b1, float* __restrict__ bias_cat) {
  int i = blockIdx.x * 256 + threadIdx.x;
  if (i >= NCAT) return;
  float v;
  if (i < 4096)      v = exp_b[i];
  else if (i < 5120) v = ds_b1[i - 4096];
  else               v = rt_b1[i - 5120];
  bias_cat[i] = v;
}

// one wave per row: router logits (4 dots of 256) + ds logit (dot of 1024)
__global__ __launch_bounds__(256)
void router_ds(const short* __restrict__ Hall,
               const float* __restrict__ rt_W2, const float* __restrict__ rt_b2,
               const float* __restrict__ ds_W2, const float* __restrict__ ds_b2,
               float* __restrict__ out_probs, float* __restrict__ out_ds)
{
  const int row  = blockIdx.x * 4 + (threadIdx.x >> 6);
  const int lane = threadIdx.x & 63;
  const short* h = Hall + (size_t)row * NCAT;
  float s0 = 0, s1 = 0, s2 = 0, s3 = 0, d = 0;
  for (int i = lane; i < 256; i += 64) {
    float v = bf2f(h[5120 + i]);
    s0 += v * rt_W2[i];
    s1 += v * rt_W2[256 + i];
    s2 += v * rt_W2[512 + i];
    s3 += v * rt_W2[768 + i];
  }
  for (int i = lane; i < 1024; i += 64)
    d += bf2f(h[4096 + i]) * ds_W2[i];
#pragma unroll
  for (int off = 32; off; off >>= 1) {
    s0 += __shfl_xor(s0, off);
    s1 += __shfl_xor(s1, off);
    s2 += __shfl_xor(s2, off);
    s3 += __shfl_xor(s3, off);
    d  += __shfl_xor(d, off);
  }
  if (lane == 0) {
    float l0 = s0 + rt_b2[0], l1 = s1 + rt_b2[1];
    float l2 = s2 + rt_b2[2], l3 = s3 + rt_b2[3];
    float mx = fmaxf(fmaxf(l0, l1), fmaxf(l2, l3));
    float e0 = expf(l0 - mx), e1 = expf(l1 - mx);
    float e2 = expf(l2 - mx), e3 = expf(l3 - mx);
    float inv = 1.f / (e0 + e1 + e2 + e3);
    out_probs[row * 4 + 0] = e0 * inv;
    out_probs[row * 4 + 1] = e1 * inv;
    out_probs[row * 4 + 2] = e2 * inv;
    out_probs[row * 4 + 3] = e3 * inv;
    out_ds[row] = 1.f / (1.f + expf(-(d + ds_b2[0])));
  }
}

// fused[b,h] = sum_e probs[b,e] * Hall[b, e*1024+h]
__global__ __launch_bounds__(256)
void fuse_experts(const short* __restrict__ Hall, const float* __restrict__ probs,
                  short* __restrict__ fused)
{
  const int idx  = blockIdx.x * 256 + threadIdx.x;
  const int b    = idx >> 10;
  const int hcol = idx & 1023;
  const short* hb = Hall + (size_t)b * NCAT;
  const float* p  = probs + (size_t)b * 4;
  float v = p[0] * bf2f(hb[hcol])        + p[1] * bf2f(hb[1024 + hcol])
          + p[2] * bf2f(hb[2048 + hcol]) + p[3] * bf2f(hb[3072 + hcol]);
  fused[idx] = f2bf(v);
}

// one block per row (768 cols): optional ds-combine, then L2-normalize -> bf16
__global__ __launch_bounds__(256)
void combine_normalize(const float* __restrict__ text, const float* __restrict__ image,
                       const float* __restrict__ ds, const float* __restrict__ src,
                       short* __restrict__ dst)
{
  const int b = blockIdx.x;
  const int t = threadIdx.x;
  const float* s = src + (size_t)b * FDIM;
  float o0, o1, o2;
  if (text != nullptr) {
    const float dv = ds[b];
    const float* tx = text + (size_t)b * FDIM;
    const float* im = image + (size_t)b * FDIM;
    o0 = dv * tx[t]       + (1.f - dv) * im[t]       + s[t];
    o1 = dv * tx[t + 256] + (1.f - dv) * im[t + 256] + s[t + 256];
    o2 = dv * tx[t + 512] + (1.f - dv) * im[t + 512] + s[t + 512];
  } else {
    o0 = s[t]; o1 = s[t + 256]; o2 = s[t + 512];
  }
  float ss = o0 * o0 + o1 * o1 + o2 * o2;
  __shared__ float red[4];
#pragma unroll
  for (int off = 32; off; off >>= 1) ss += __shfl_xor(ss, off);
  if ((t & 63) == 0) red[t >> 6] = ss;
  __syncthreads();
  const float tot = red[0] + red[1] + red[2] + red[3];
  const float rn = 1.f / fmaxf(sqrtf(tot), 1e-12f);
  short* d = dst + (size_t)b * FDIM;
  d[t]       = f2bf(o0 * rn);
  d[t + 256] = f2bf(o1 * rn);
  d[t + 512] = f2bf(o2 * rn);
}

// ---------------------------------------------------------------------------
extern "C" void kernel_launch(void* const* d_in, const int* in_sizes, int n_in,
                              void* d_out, int out_size, void* d_ws, size_t ws_size,
                              hipStream_t stream) {
  const float* image  = (const float*)d_in[0];
  const float* text   = (const float*)d_in[1];
  const float* target = (const float*)d_in[2];
  const float* Wt     = (const float*)d_in[3];
  const float* bt     = (const float*)d_in[4];
  const float* Wi     = (const float*)d_in[5];
  const float* bi     = (const float*)d_in[6];
  const float* ds_W1  = (const float*)d_in[7];
  const float* ds_b1  = (const float*)d_in[8];
  const float* ds_W2  = (const float*)d_in[9];
  const float* ds_b2  = (const float*)d_in[10];
  const float* exp_W  = (const float*)d_in[11];
  const float* exp_b  = (const float*)d_in[12];
  const float* rt_W1  = (const float*)d_in[13];
  const float* rt_b1  = (const float*)d_in[14];
  const float* rt_W2  = (const float*)d_in[15];
  const float* rt_b2  = (const float*)d_in[16];
  const float* out_W  = (const float*)d_in[17];
  const float* out_b  = (const float*)d_in[18];
  const float* logit_scale = (const float*)d_in[19];

  char* ws = (char*)d_ws;
  short* comb  = (short*)ws;  ws += (size_t)BDIM * 1024 * 2;
  short* Hall  = (short*)ws;  ws += (size_t)BDIM * NCAT * 2;
  short* fused = (short*)ws;  ws += (size_t)BDIM * 1024 * 2;
  float* resid = (float*)ws;  ws += (size_t)BDIM * FDIM * 4;
  short* pred  = (short*)ws;  ws += (size_t)BDIM * FDIM * 2;
  short* tgtb  = (short*)ws;  ws += (size_t)TDIM * FDIM * 2;
  short* textb = (short*)ws;  ws += (size_t)BDIM * FDIM * 2;
  short* imgb  = (short*)ws;  ws += (size_t)BDIM * FDIM * 2;
  short* Wtb   = (short*)ws;  ws += (size_t)PDIM * FDIM * 2;
  short* Wib   = (short*)ws;  ws += (size_t)PDIM * FDIM * 2;
  short* outWb = (short*)ws;  ws += (size_t)FDIM * HDIM * 2;
  short* Bcat  = (short*)ws;  ws += (size_t)NCAT * HDIM * 2;
  float* biascat = (float*)ws; ws += (size_t)NCAT * 4;

  float* out_logits = (float*)d_out;
  float* out_ds     = out_logits + (size_t)BDIM * TDIM;
  float* out_probs  = out_ds + BDIM;

  // --- prep: convert to bf16 / build concatenated weights ---
  {
    int n;
    n = BDIM * FDIM;  f32_to_bf16<<<(n + 255) / 256, 256, 0, stream>>>(text,  textb, n);
    n = BDIM * FDIM;  f32_to_bf16<<<(n + 255) / 256, 256, 0, stream>>>(image, imgb,  n);
    n = PDIM * FDIM;  f32_to_bf16<<<(n + 255) / 256, 256, 0, stream>>>(Wt,    Wtb,   n);
    n = PDIM * FDIM;  f32_to_bf16<<<(n + 255) / 256, 256, 0, stream>>>(Wi,    Wib,   n);
    n = NEXP * HDIM * 1024; f32_to_bf16<<<(n + 255) / 256, 256, 0, stream>>>(exp_W, Bcat, n);
    n = HDIM * 1024;  f32_to_bf16<<<(n + 255) / 256, 256, 0, stream>>>(ds_W1, Bcat + (size_t)4096 * 1024, n);
    n = 256 * 1024;   f32_to_bf16<<<(n + 255) / 256, 256, 0, stream>>>(rt_W1, Bcat + (size_t)5120 * 1024, n);
    n = FDIM * HDIM;  f32_to_bf16<<<(n + 255) / 256, 256, 0, stream>>>(out_W, outWb, n);
    concat_bias<<<(NCAT + 255) / 256, 256, 0, stream>>>(exp_b, ds_b1, rt_b1, biascat);
  }

  dim3 blk(256);
  // comb = [gelu(text@Wt.T+bt), gelu(image@Wi.T+bi)]  -> bf16 [B,1024]
  gemm_bt<0><<<dim3(PDIM / 128, BDIM / 128), blk, 0, stream>>>(textb, FDIM, Wtb, FDIM, comb,        1024, FDIM, bt, nullptr);
  gemm_bt<0><<<dim3(PDIM / 128, BDIM / 128), blk, 0, stream>>>(imgb,  FDIM, Wib, FDIM, comb + 512,  1024, FDIM, bi, nullptr);
  // Hall = gelu(comb @ [exp_W;ds_W1;rt_W1].T + bias) -> bf16 [B,5376]
  gemm_bt<0><<<dim3(NCAT / 128, BDIM / 128), blk, 0, stream>>>(comb, 1024, Bcat, 1024, Hall, NCAT, 1024, biascat, nullptr);
  // router probs + ds scalar
  router_ds<<<BDIM / 4, 256, 0, stream>>>(Hall, rt_W2, rt_b2, ds_W2, ds_b2, out_probs, out_ds);
  // fused hidden
  fuse_experts<<<(BDIM * HDIM) / 256, 256, 0, stream>>>(Hall, out_probs, fused);
  // residual = fused @ out_W.T + out_b -> f32 [B,768]
  gemm_bt<1><<<dim3(FDIM / 128, BDIM / 128), blk, 0, stream>>>(fused, 1024, outWb, 1024, resid, FDIM, 1024, out_b, nullptr);
  // pred = normalize(ds*text + (1-ds)*image + resid) -> bf16
  combine_normalize<<<BDIM, 256, 0, stream>>>(text, image, out_ds, resid, pred);
  // tgt = normalize(target) -> bf16
  combine_normalize<<<TDIM, 256, 0, stream>>>(nullptr, nullptr, nullptr, target, tgtb);
  // logits = exp(logit_scale) * pred @ tgt.T -> f32 [B,T]
  gemm_bt<2><<<dim3(TDIM / 128, BDIM / 128), blk, 0, stream>>>(pred, FDIM, tgtb, FDIM, out_logits, TDIM, FDIM, nullptr, logit_scale);
}

// Round 2
// 667.204 us; speedup vs baseline: 1.1007x; 1.1007x over previous
//
#include <hip/hip_runtime.h>
#include <stdint.h>
#include <math.h>

// Problem dims
#define BDIM 8192
#define TDIM 8192
#define FDIM 768
#define PDIM 512
#define HDIM 1024
#define NEXP 4
#define NCAT 5376  // 4*1024 (experts) + 1024 (ds) + 256 (router)

using short4v = __attribute__((ext_vector_type(4))) short;
using short8 = __attribute__((ext_vector_type(8))) short;
using f32x4  = __attribute__((ext_vector_type(4))) float;

__device__ __forceinline__ short f2bf(float f) {
  uint32_t u = __builtin_bit_cast(uint32_t, f);
  u += 0x7fffu + ((u >> 16) & 1u);   // RNE
  return (short)(u >> 16);
}
__device__ __forceinline__ float bf2f(short s) {
  uint32_t u = ((uint32_t)(uint16_t)s) << 16;
  return __builtin_bit_cast(float, u);
}
__device__ __forceinline__ float gelu_exact(float x) {
  return 0.5f * x * (1.0f + erff(x * 0.70710678118654752f));
}

#define GLDS(gp, lp) __builtin_amdgcn_global_load_lds( \
    (const __attribute__((address_space(1))) void*)(gp), \
    (__attribute__((address_space(3))) void*)(lp), 16, 0, 0)

// ---------------------------------------------------------------------------
// Shared GEMM body: C[M,N] = A[M,K] @ B[N,K]^T (row-major bf16-as-short).
// 128x128 block tile, 4 waves, 4x4 of 16x16x32 MFMA each, BK=32.
// MODE 0: +bias[col], gelu, store bf16
// MODE 1: +bias[col], store f32
// MODE 2: *scale, store f32
// ---------------------------------------------------------------------------
template <int MODE>
__device__ __forceinline__ void gemm_body(
    const short* __restrict__ A, int lda,
    const short* __restrict__ B, int ldb,
    void* __restrict__ C, int ldc, int K,
    const float* __restrict__ bias, float scale,
    int m0, int n0)
{
  __shared__ short sA[4096];  // 128 x 32
  __shared__ short sB[4096];
  const int t    = threadIdx.x;
  const int lane = t & 63;
  const int wave = t >> 6;
  const int wm = (wave >> 1) * 64;
  const int wn = (wave & 1) * 64;
  const int l15  = lane & 15;
  const int quad = lane >> 4;

  f32x4 acc[4][4];
#pragma unroll
  for (int i = 0; i < 4; ++i)
#pragma unroll
    for (int j = 0; j < 4; ++j)
      acc[i][j] = (f32x4){0.f, 0.f, 0.f, 0.f};

  const int rr = t >> 2;
  const int cc = (t & 3) * 8;
  const short* gA0 = A + (size_t)(m0 + rr) * lda + cc;
  const short* gA1 = A + (size_t)(m0 + 64 + rr) * lda + cc;
  const short* gB0 = B + (size_t)(n0 + rr) * ldb + cc;
  const short* gB1 = B + (size_t)(n0 + 64 + rr) * ldb + cc;
  short* lA0 = sA + t * 8;
  short* lA1 = sA + 2048 + t * 8;
  short* lB0 = sB + t * 8;
  short* lB1 = sB + 2048 + t * 8;

  for (int k0 = 0; k0 < K; k0 += 32) {
    GLDS(gA0 + k0, lA0);
    GLDS(gA1 + k0, lA1);
    GLDS(gB0 + k0, lB0);
    GLDS(gB1 + k0, lB1);
    __syncthreads();
    short8 af[4], bfr[4];
#pragma unroll
    for (int i = 0; i < 4; ++i)
      af[i] = *(const short8*)(sA + (wm + i * 16 + l15) * 32 + quad * 8);
#pragma unroll
    for (int j = 0; j < 4; ++j)
      bfr[j] = *(const short8*)(sB + (wn + j * 16 + l15) * 32 + quad * 8);
#pragma unroll
    for (int i = 0; i < 4; ++i)
#pragma unroll
      for (int j = 0; j < 4; ++j)
        acc[i][j] = __builtin_amdgcn_mfma_f32_16x16x32_bf16(af[i], bfr[j], acc[i][j], 0, 0, 0);
    __syncthreads();
  }

#pragma unroll
  for (int i = 0; i < 4; ++i) {
#pragma unroll
    for (int j = 0; j < 4; ++j) {
      const int col = n0 + wn + j * 16 + l15;
      float bv = (MODE == 2) ? 0.f : bias[col];
#pragma unroll
      for (int r = 0; r < 4; ++r) {
        const int row = m0 + wm + i * 16 + quad * 4 + r;  // C/D: col=lane&15, row=quad*4+reg
        float v = acc[i][j][r];
        if (MODE == 0) {
          v = gelu_exact(v + bv);
          ((short*)C)[(size_t)row * ldc + col] = f2bf(v);
        } else if (MODE == 1) {
          ((float*)C)[(size_t)row * ldc + col] = v + bv;
        } else {
          ((float*)C)[(size_t)row * ldc + col] = v * scale;
        }
      }
    }
  }
}

template <int MODE>
__global__ __launch_bounds__(256, 2)
void gemm_bt(const short* __restrict__ A, int lda,
             const short* __restrict__ B, int ldb,
             void* __restrict__ C, int ldc, int K,
             const float* __restrict__ bias,
             const float* __restrict__ scale_ptr)
{
  float scale = 1.f;
  if (MODE == 2) scale = expf(scale_ptr[0]);
  gemm_body<MODE>(A, lda, B, ldb, C, ldc, K, bias, scale,
                  blockIdx.y * 128, blockIdx.x * 128);
}

// both projections in one launch: z=0 -> text@Wt.T (cols 0..511),
// z=1 -> image@Wi.T (cols 512..1023); C is comb [B,1024] bf16
__global__ __launch_bounds__(256, 2)
void gemm_proj(const short* __restrict__ textb, const short* __restrict__ imgb,
               const short* __restrict__ Wtb, const short* __restrict__ Wib,
               const float* __restrict__ bt, const float* __restrict__ bi,
               short* __restrict__ comb)
{
  const int z = blockIdx.z;
  const short* A = z ? imgb : textb;
  const short* B = z ? Wib : Wtb;
  const float* bias = z ? bi : bt;
  short* C = comb + (z ? 512 : 0);
  gemm_body<0>(A, FDIM, B, FDIM, C, 1024, FDIM, bias, 1.f,
               blockIdx.y * 128, blockIdx.x * 128);
}

// ---------------------------------------------------------------------------
// One kernel for ALL f32->bf16 conversions + bias concat. Flat grid over
// vec4 units with hardcoded segment boundaries.
// ---------------------------------------------------------------------------
#define SEG0 1572864u   // text   (8192*768/4)
#define SEG1 3145728u   // image
#define SEG2 3244032u   // Wt     (512*768/4)
#define SEG3 3342336u   // Wi
#define SEG4 4390912u   // exp_W  (4*1024*1024/4)
#define SEG5 4653056u   // ds_W1  (1024*1024/4)
#define SEG6 4718592u   // rt_W1  (256*1024/4)
#define SEG7 4915200u   // out_W  (768*1024/4)
#define SEG8 4916544u   // bias concat (5376/4)

__global__ __launch_bounds__(256)
void prep_all(const float* __restrict__ text, const float* __restrict__ image,
              const float* __restrict__ Wt, const float* __restrict__ Wi,
              const float* __restrict__ exp_W, const float* __restrict__ ds_W1,
              const float* __restrict__ rt_W1, const float* __restrict__ out_W,
              const float* __restrict__ exp_b, const float* __restrict__ ds_b1,
              const float* __restrict__ rt_b1,
              short* __restrict__ textb, short* __restrict__ imgb,
              short* __restrict__ Wtb, short* __restrict__ Wib,
              short* __restrict__ Bcat, short* __restrict__ outWb,
              float* __restrict__ biascat)
{
  const uint32_t i = blockIdx.x * 256 + threadIdx.x;
  if (i >= SEG8) return;
  if (i >= SEG7) {  // bias concat (f32 -> f32)
    const uint32_t j = (i - SEG7) * 4;
#pragma unroll
    for (int k = 0; k < 4; ++k) {
      uint32_t idx = j + k;
      float v;
      if (idx < 4096)      v = exp_b[idx];
      else if (idx < 5120) v = ds_b1[idx - 4096];
      else                 v = rt_b1[idx - 5120];
      biascat[idx] = v;
    }
    return;
  }
  const float* s;
  short* d;
  uint32_t j;
  if (i < SEG1) {
    if (i < SEG0) { j = i;        s = text;  d = textb; }
    else          { j = i - SEG0; s = image; d = imgb;  }
  } else if (i < SEG3) {
    if (i < SEG2) { j = i - SEG1; s = Wt; d = Wtb; }
    else          { j = i - SEG2; s = Wi; d = Wib; }
  } else if (i < SEG5) {
    if (i < SEG4) { j = i - SEG3; s = exp_W; d = Bcat; }
    else          { j = i - SEG4; s = ds_W1; d = Bcat + (size_t)4096 * 1024; }
  } else {
    if (i < SEG6) { j = i - SEG5; s = rt_W1; d = Bcat + (size_t)5120 * 1024; }
    else          { j = i - SEG6; s = out_W; d = outWb; }
  }
  float4 v = ((const float4*)s)[j];
  short4v o = { f2bf(v.x), f2bf(v.y), f2bf(v.z), f2bf(v.w) };
  ((short4v*)d)[j] = o;
}

// ---------------------------------------------------------------------------
// Fused router + ds scalar + expert mixing. One block (256 thr) per row.
// Reads the Hall row once: router logits, softmax, ds sigmoid, fused hidden.
// ---------------------------------------------------------------------------
__global__ __launch_bounds__(256)
void moe_mix(const short* __restrict__ Hall,
             const float* __restrict__ rt_W2, const float* __restrict__ rt_b2,
             const float* __restrict__ ds_W2, const float* __restrict__ ds_b2,
             float* __restrict__ out_probs, float* __restrict__ out_ds,
             short* __restrict__ fused)
{
  const int b = blockIdx.x;
  const int t = threadIdx.x;
  const int lane = t & 63;
  const int wave = t >> 6;
  const short* h = Hall + (size_t)b * NCAT;

  // router partials (256 elems, one per thread) + ds partials (1024 elems)
  float rv = bf2f(h[5120 + t]);
  float p0 = rv * rt_W2[t];
  float p1 = rv * rt_W2[256 + t];
  float p2 = rv * rt_W2[512 + t];
  float p3 = rv * rt_W2[768 + t];
  float dd = 0.f;
#pragma unroll
  for (int k = 0; k < 4; ++k)
    dd += bf2f(h[4096 + k * 256 + t]) * ds_W2[k * 256 + t];

#pragma unroll
  for (int off = 32; off; off >>= 1) {
    p0 += __shfl_xor(p0, off);
    p1 += __shfl_xor(p1, off);
    p2 += __shfl_xor(p2, off);
    p3 += __shfl_xor(p3, off);
    dd += __shfl_xor(dd, off);
  }
  __shared__ float red[5][4];
  __shared__ float bc[5];
  if (lane == 0) {
    red[0][wave] = p0; red[1][wave] = p1; red[2][wave] = p2;
    red[3][wave] = p3; red[4][wave] = dd;
  }
  __syncthreads();
  if (t == 0) {
    float l0 = red[0][0] + red[0][1] + red[0][2] + red[0][3] + rt_b2[0];
    float l1 = red[1][0] + red[1][1] + red[1][2] + red[1][3] + rt_b2[1];
    float l2 = red[2][0] + red[2][1] + red[2][2] + red[2][3] + rt_b2[2];
    float l3 = red[3][0] + red[3][1] + red[3][2] + red[3][3] + rt_b2[3];
    float d  = red[4][0] + red[4][1] + red[4][2] + red[4][3] + ds_b2[0];
    float mx = fmaxf(fmaxf(l0, l1), fmaxf(l2, l3));
    float e0 = expf(l0 - mx), e1 = expf(l1 - mx);
    float e2 = expf(l2 - mx), e3 = expf(l3 - mx);
    float inv = 1.f / (e0 + e1 + e2 + e3);
    bc[0] = e0 * inv; bc[1] = e1 * inv; bc[2] = e2 * inv; bc[3] = e3 * inv;
    bc[4] = 1.f / (1.f + expf(-d));
    out_probs[b * 4 + 0] = bc[0];
    out_probs[b * 4 + 1] = bc[1];
    out_probs[b * 4 + 2] = bc[2];
    out_probs[b * 4 + 3] = bc[3];
    out_ds[b] = bc[4];
  }
  __syncthreads();
  const float q0 = bc[0], q1 = bc[1], q2 = bc[2], q3 = bc[3];
  short* fr = fused + (size_t)b * 1024;
#pragma unroll
  for (int c = t; c < 1024; c += 256) {
    float v = q0 * bf2f(h[c])        + q1 * bf2f(h[1024 + c])
            + q2 * bf2f(h[2048 + c]) + q3 * bf2f(h[3072 + c]);
    fr[c] = f2bf(v);
  }
}

// ---------------------------------------------------------------------------
// Both normalizes in one launch. blocks [0,BDIM): pred (combine+normalize);
// blocks [BDIM, BDIM+TDIM): tgt (normalize target).
// ---------------------------------------------------------------------------
__global__ __launch_bounds__(256)
void normalize_both(const float* __restrict__ text, const float* __restrict__ image,
                    const float* __restrict__ ds, const float* __restrict__ resid,
                    const float* __restrict__ target,
                    short* __restrict__ pred, short* __restrict__ tgtb)
{
  const int bb = blockIdx.x;
  const int t = threadIdx.x;
  float o0, o1, o2;
  short* d;
  if (bb < BDIM) {
    const float dv = ds[bb];
    const float* tx = text + (size_t)bb * FDIM;
    const float* im = image + (size_t)bb * FDIM;
    const float* s  = resid + (size_t)bb * FDIM;
    o0 = dv * tx[t]       + (1.f - dv) * im[t]       + s[t];
    o1 = dv * tx[t + 256] + (1.f - dv) * im[t + 256] + s[t + 256];
    o2 = dv * tx[t + 512] + (1.f - dv) * im[t + 512] + s[t + 512];
    d = pred + (size_t)bb * FDIM;
  } else {
    const int b = bb - BDIM;
    const float* s = target + (size_t)b * FDIM;
    o0 = s[t]; o1 = s[t + 256]; o2 = s[t + 512];
    d = tgtb + (size_t)b * FDIM;
  }
  float ss = o0 * o0 + o1 * o1 + o2 * o2;
  __shared__ float red[4];
#pragma unroll
  for (int off = 32; off; off >>= 1) ss += __shfl_xor(ss, off);
  if ((t & 63) == 0) red[t >> 6] = ss;
  __syncthreads();
  const float tot = red[0] + red[1] + red[2] + red[3];
  const float rn = 1.f / fmaxf(sqrtf(tot), 1e-12f);
  d[t]       = f2bf(o0 * rn);
  d[t + 256] = f2bf(o1 * rn);
  d[t + 512] = f2bf(o2 * rn);
}

// ---------------------------------------------------------------------------
extern "C" void kernel_launch(void* const* d_in, const int* in_sizes, int n_in,
                              void* d_out, int out_size, void* d_ws, size_t ws_size,
                              hipStream_t stream) {
  const float* image  = (const float*)d_in[0];
  const float* text   = (const float*)d_in[1];
  const float* target = (const float*)d_in[2];
  const float* Wt     = (const float*)d_in[3];
  const float* bt     = (const float*)d_in[4];
  const float* Wi     = (const float*)d_in[5];
  const float* bi     = (const float*)d_in[6];
  const float* ds_W1  = (const float*)d_in[7];
  const float* ds_b1  = (const float*)d_in[8];
  const float* ds_W2  = (const float*)d_in[9];
  const float* ds_b2  = (const float*)d_in[10];
  const float* exp_W  = (const float*)d_in[11];
  const float* exp_b  = (const float*)d_in[12];
  const float* rt_W1  = (const float*)d_in[13];
  const float* rt_b1  = (const float*)d_in[14];
  const float* rt_W2  = (const float*)d_in[15];
  const float* rt_b2  = (const float*)d_in[16];
  const float* out_W  = (const float*)d_in[17];
  const float* out_b  = (const float*)d_in[18];
  const float* logit_scale = (const float*)d_in[19];

  char* ws = (char*)d_ws;
  short* comb  = (short*)ws;  ws += (size_t)BDIM * 1024 * 2;
  short* Hall  = (short*)ws;  ws += (size_t)BDIM * NCAT * 2;
  short* fused = (short*)ws;  ws += (size_t)BDIM * 1024 * 2;
  float* resid = (float*)ws;  ws += (size_t)BDIM * FDIM * 4;
  short* pred  = (short*)ws;  ws += (size_t)BDIM * FDIM * 2;
  short* tgtb  = (short*)ws;  ws += (size_t)TDIM * FDIM * 2;
  short* textb = (short*)ws;  ws += (size_t)BDIM * FDIM * 2;
  short* imgb  = (short*)ws;  ws += (size_t)BDIM * FDIM * 2;
  short* Wtb   = (short*)ws;  ws += (size_t)PDIM * FDIM * 2;
  short* Wib   = (short*)ws;  ws += (size_t)PDIM * FDIM * 2;
  short* outWb = (short*)ws;  ws += (size_t)FDIM * HDIM * 2;
  short* Bcat  = (short*)ws;  ws += (size_t)NCAT * HDIM * 2;
  float* biascat = (float*)ws; ws += (size_t)NCAT * 4;

  float* out_logits = (float*)d_out;
  float* out_ds     = out_logits + (size_t)BDIM * TDIM;
  float* out_probs  = out_ds + BDIM;

  // 1. all conversions + bias concat in one launch
  prep_all<<<(SEG8 + 255) / 256, 256, 0, stream>>>(
      text, image, Wt, Wi, exp_W, ds_W1, rt_W1, out_W,
      exp_b, ds_b1, rt_b1,
      textb, imgb, Wtb, Wib, Bcat, outWb, biascat);

  dim3 blk(256);
  // 2. comb = [gelu(text@Wt.T+bt), gelu(image@Wi.T+bi)] -> bf16 [B,1024]
  gemm_proj<<<dim3(PDIM / 128, BDIM / 128, 2), blk, 0, stream>>>(
      textb, imgb, Wtb, Wib, bt, bi, comb);
  // 3. Hall = gelu(comb @ [exp_W;ds_W1;rt_W1].T + bias) -> bf16 [B,5376]
  gemm_bt<0><<<dim3(NCAT / 128, BDIM / 128), blk, 0, stream>>>(
      comb, 1024, Bcat, 1024, Hall, NCAT, 1024, biascat, nullptr);
  // 4. router probs + ds + fused hidden (single pass over Hall)
  moe_mix<<<BDIM, 256, 0, stream>>>(Hall, rt_W2, rt_b2, ds_W2, ds_b2,
                                    out_probs, out_ds, fused);
  // 5. residual = fused @ out_W.T + out_b -> f32 [B,768]
  gemm_bt<1><<<dim3(FDIM / 128, BDIM / 128), blk, 0, stream>>>(
      fused, 1024, outWb, 1024, resid, FDIM, 1024, out_b, nullptr);
  // 6. pred + tgt normalize in one launch
  normalize_both<<<BDIM + TDIM, 256, 0, stream>>>(
      text, image, out_ds, resid, target, pred, tgtb);
  // 7. logits = exp(logit_scale) * pred @ tgt.T -> f32 [B,T]
  gemm_bt<2><<<dim3(TDIM / 128, BDIM / 128), blk, 0, stream>>>(
      pred, FDIM, tgtb, FDIM, out_logits, TDIM, FDIM, nullptr, logit_scale);
}